// Round 3
// baseline (223.306 us; speedup 1.0000x reference)
//
#include <hip/hip_runtime.h>

#define VOCAB 128000
#define DIM 2048
#define NTOK 8192
#define RO_BLOCKS (VOCAB / 4)   // 4 rows/block, 1 row/wave

__device__ __forceinline__ float qclip(float w) {
  // jnp.clip(jnp.round(w), -128, 127); rintf == round-half-even == jnp.round
  return fminf(fmaxf(rintf(w), -128.0f), 127.0f);
}

// ---------------------------------------------------------------------------
// Preprocess: per-row linked list of token positions.
// head[row] -> most recent t with tokens[t]==row; next[t] -> previous, -1 ends.
// Output writes in the main kernel are disjoint per t, so list order (atomic
// race order) does not affect the result: deterministic.
// ---------------------------------------------------------------------------
__global__ __launch_bounds__(256) void init_heads_kernel(int* __restrict__ head) {
  const int i = blockIdx.x * 256 + threadIdx.x;
  if (i < VOCAB) head[i] = -1;
}

__global__ __launch_bounds__(256) void build_lists_kernel(
    const int* __restrict__ tokens, int* __restrict__ head,
    int* __restrict__ next) {
  const int t = blockIdx.x * 256 + threadIdx.x;
  if (t < NTOK) {
    const int row = tokens[t];
    next[t] = atomicExch(&head[row], t);
  }
}

// ---------------------------------------------------------------------------
// Main: one wave per vocab row.
//   - stream W row (8 x float4/lane, HBM) into registers, fake-quantize
//   - inline per-wave activation absmax quant (x is L2-resident)
//   - dot -> out_readout[row]
//   - for each token position t with tokens[t]==row: write the register-held
//     dequantized row to out_embed[t,:]  (zero extra HBM reads)
// ---------------------------------------------------------------------------
__global__ __launch_bounds__(256) void fused_readout_embed_kernel(
    const float* __restrict__ W, const float* __restrict__ scales,
    const float* __restrict__ x, const int* __restrict__ head,
    const int* __restrict__ next, float* __restrict__ out_embed,
    float* __restrict__ out_readout) {
  const int wid = threadIdx.x >> 6;
  const int lane = threadIdx.x & 63;
  const int row = blockIdx.x * 4 + wid;

  const float4* __restrict__ xv = reinterpret_cast<const float4*>(x);
  const float4* __restrict__ wrow =
      reinterpret_cast<const float4*>(W + (size_t)row * DIM);

  // Issue x loads first (L2-resident, low latency)...
  float4 xl[8];
  #pragma unroll
  for (int k = 0; k < 8; ++k) xl[k] = xv[lane + k * 64];

  // ...then the W stream (HBM) so all 16 loads are in flight while we
  // process x below.
  float4 wq[8];
  #pragma unroll
  for (int k = 0; k < 8; ++k) wq[k] = wrow[lane + k * 64];

  const int tok0 = head[row];

  // Per-wave activation quant: 64 lanes x 8 float4 cover all DIM=2048 elems,
  // identical fp32 arithmetic in every wave -> same scale everywhere.
  float m = 0.0f;
  #pragma unroll
  for (int k = 0; k < 8; ++k) {
    m = fmaxf(m, fmaxf(fmaxf(fabsf(xl[k].x), fabsf(xl[k].y)),
                       fmaxf(fabsf(xl[k].z), fabsf(xl[k].w))));
  }
  #pragma unroll
  for (int off = 32; off > 0; off >>= 1) m = fmaxf(m, __shfl_xor(m, off, 64));
  const float scale = fmaxf(m / 127.0f, 1e-12f);
  const float rcp = 1.0f / scale;
  #pragma unroll
  for (int k = 0; k < 8; ++k) {
    xl[k].x = fminf(fmaxf(rintf(xl[k].x * rcp), -128.0f), 127.0f) * scale;
    xl[k].y = fminf(fmaxf(rintf(xl[k].y * rcp), -128.0f), 127.0f) * scale;
    xl[k].z = fminf(fmaxf(rintf(xl[k].z * rcp), -128.0f), 127.0f) * scale;
    xl[k].w = fminf(fmaxf(rintf(xl[k].w * rcp), -128.0f), 127.0f) * scale;
  }

  // Quantize W in place (kept for the embed writes) and accumulate the dot.
  float acc = 0.0f;
  #pragma unroll
  for (int k = 0; k < 8; ++k) {
    wq[k].x = qclip(wq[k].x);
    wq[k].y = qclip(wq[k].y);
    wq[k].z = qclip(wq[k].z);
    wq[k].w = qclip(wq[k].w);
    acc += wq[k].x * xl[k].x;
    acc += wq[k].y * xl[k].y;
    acc += wq[k].z * xl[k].z;
    acc += wq[k].w * xl[k].w;
  }
  #pragma unroll
  for (int off = 32; off > 0; off >>= 1) acc += __shfl_down(acc, off, 64);
  const float srow = scales[row];
  if (lane == 0) out_readout[row] = acc * srow;

  // Embed writes: walk this row's token list (wave-uniform branch; ~6% of
  // rows take it). Row data is already in wq registers.
  int t = tok0;
  while (t >= 0) {
    float4* __restrict__ orow =
        reinterpret_cast<float4*>(out_embed + (size_t)t * DIM);
    #pragma unroll
    for (int k = 0; k < 8; ++k) {
      float4 r;
      r.x = wq[k].x * srow;
      r.y = wq[k].y * srow;
      r.z = wq[k].z * srow;
      r.w = wq[k].w * srow;
      orow[lane + k * 64] = r;
    }
    t = next[t];
  }
}

// ---------------------------------------------------------------------------
// Fallback (R2 kernel) in case ws_size is too small for head/next.
// ---------------------------------------------------------------------------
__global__ __launch_bounds__(256) void fallback_fused_kernel(
    const float* __restrict__ W, const float* __restrict__ scales,
    const int* __restrict__ tokens, const float* __restrict__ x,
    float* __restrict__ out_embed, float* __restrict__ out_readout) {
  const int b = blockIdx.x;
  if (b < NTOK) {
    const int tok = tokens[b];
    const float s = scales[tok];
    const float4* __restrict__ wrow =
        reinterpret_cast<const float4*>(W + (size_t)tok * DIM);
    float4* __restrict__ orow =
        reinterpret_cast<float4*>(out_embed + (size_t)b * DIM);
    #pragma unroll
    for (int k = 0; k < 2; ++k) {
      const int i = threadIdx.x + k * 256;
      float4 w4 = wrow[i];
      float4 r;
      r.x = qclip(w4.x) * s;
      r.y = qclip(w4.y) * s;
      r.z = qclip(w4.z) * s;
      r.w = qclip(w4.w) * s;
      orow[i] = r;
    }
    return;
  }
  const int rb = b - NTOK;
  const int wid = threadIdx.x >> 6;
  const int lane = threadIdx.x & 63;
  const int row = rb * 4 + wid;
  const float4* __restrict__ xv = reinterpret_cast<const float4*>(x);
  float4 xl[8];
  float m = 0.0f;
  #pragma unroll
  for (int k = 0; k < 8; ++k) {
    xl[k] = xv[lane + k * 64];
    m = fmaxf(m, fmaxf(fmaxf(fabsf(xl[k].x), fabsf(xl[k].y)),
                       fmaxf(fabsf(xl[k].z), fabsf(xl[k].w))));
  }
  #pragma unroll
  for (int off = 32; off > 0; off >>= 1) m = fmaxf(m, __shfl_xor(m, off, 64));
  const float scale = fmaxf(m / 127.0f, 1e-12f);
  const float rcp = 1.0f / scale;
  #pragma unroll
  for (int k = 0; k < 8; ++k) {
    xl[k].x = fminf(fmaxf(rintf(xl[k].x * rcp), -128.0f), 127.0f) * scale;
    xl[k].y = fminf(fmaxf(rintf(xl[k].y * rcp), -128.0f), 127.0f) * scale;
    xl[k].z = fminf(fmaxf(rintf(xl[k].z * rcp), -128.0f), 127.0f) * scale;
    xl[k].w = fminf(fmaxf(rintf(xl[k].w * rcp), -128.0f), 127.0f) * scale;
  }
  const float4* __restrict__ wrow =
      reinterpret_cast<const float4*>(W + (size_t)row * DIM);
  float acc = 0.0f;
  #pragma unroll
  for (int k = 0; k < 8; ++k) {
    float4 w4 = wrow[lane + k * 64];
    acc += qclip(w4.x) * xl[k].x;
    acc += qclip(w4.y) * xl[k].y;
    acc += qclip(w4.z) * xl[k].z;
    acc += qclip(w4.w) * xl[k].w;
  }
  #pragma unroll
  for (int off = 32; off > 0; off >>= 1) acc += __shfl_down(acc, off, 64);
  if (lane == 0) out_readout[row] = acc * scales[row];
}

// ---------------------------------------------------------------------------
extern "C" void kernel_launch(void* const* d_in, const int* in_sizes, int n_in,
                              void* d_out, int out_size, void* d_ws, size_t ws_size,
                              hipStream_t stream) {
  const float* W      = (const float*)d_in[0];   // [VOCAB, DIM]
  const float* scales = (const float*)d_in[1];   // [VOCAB]
  const int*   tokens = (const int*)d_in[2];     // [NTOK]
  const float* x      = (const float*)d_in[3];   // [DIM]

  float* out_embed   = (float*)d_out;                       // [NTOK, DIM]
  float* out_readout = (float*)d_out + (size_t)NTOK * DIM;  // [VOCAB]

  const size_t need = (size_t)(VOCAB + NTOK) * sizeof(int);
  if (ws_size >= need) {
    int* head = (int*)d_ws;          // [VOCAB]
    int* next = head + VOCAB;        // [NTOK]
    init_heads_kernel<<<(VOCAB + 255) / 256, 256, 0, stream>>>(head);
    build_lists_kernel<<<(NTOK + 255) / 256, 256, 0, stream>>>(tokens, head, next);
    fused_readout_embed_kernel<<<RO_BLOCKS, 256, 0, stream>>>(
        W, scales, x, head, next, out_embed, out_readout);
  } else {
    fallback_fused_kernel<<<NTOK + RO_BLOCKS, 256, 0, stream>>>(
        W, scales, tokens, x, out_embed, out_readout);
  }
}